// Round 1
// baseline (5580.322 us; speedup 1.0000x reference)
//
#include <hip/hip_runtime.h>
#include <cmath>

#define NHEAD 12
#define NTOK 49
#define CDIM 768
#define C2DIM 384
#define HDIM 64
#define HD2 32
#define TSEL 32
#define BATCH 2048
constexpr float SCALE_Q = 0.125f; // 64^-0.5

// ---------------------------------------------------------------------------
// GEMM: C[M,Nout] = A[M,K] @ W[Nout,K]^T + bias
// MODE 0: plain row-major A (lda = K)
// MODE 1: A element (m, kg) gathered from q: nh=kg>>5, j=kg&31,
//         q[m*768 + nh*64 + cidx[(b*12+nh)*32 + j]],  b = m/49   (K=384)
// MODE 2: A element (m, kg) gathered from q: b=m>>5, t=m&31, nh=kg>>6,
//         q[(b*49 + p[(b*12+nh)*32 + t])*768 + kg]               (K=768)
// ---------------------------------------------------------------------------
template <int MODE>
__global__ __launch_bounds__(256) void gemm_kernel(
    const float* __restrict__ A, const float* __restrict__ W,
    const float* __restrict__ bias, float* __restrict__ C,
    int M, int Nout, int K, const int* __restrict__ gidx)
{
    __shared__ float As[16][68];
    __shared__ float Bs[16][68];
    const int tid = threadIdx.x;
    const int mBase = blockIdx.x * 64;
    const int nBase = blockIdx.y * 64;
    const int ty = tid >> 4, tx = tid & 15;
    const int r = tid >> 2, kq = tid & 3; // staging coords: row r, k-quad kq

    float acc[4][4] = {};

    for (int kBase = 0; kBase < K; kBase += 16) {
        __syncthreads();
        // ---- stage A tile (64 rows x 16 k) transposed into As[k][row]
        if (MODE == 0) {
            const float4 av = *reinterpret_cast<const float4*>(
                &A[(size_t)(mBase + r) * K + kBase + kq * 4]);
            As[kq * 4 + 0][r] = av.x; As[kq * 4 + 1][r] = av.y;
            As[kq * 4 + 2][r] = av.z; As[kq * 4 + 3][r] = av.w;
        } else if (MODE == 1) {
            const int gm = mBase + r;
            const int b = gm / NTOK;
            #pragma unroll
            for (int u = 0; u < 4; u++) {
                const int kg = kBase + kq * 4 + u;
                const int nh = kg >> 5, j = kg & 31;
                const int ci = gidx[(b * NHEAD + nh) * HD2 + j];
                As[kq * 4 + u][r] = A[(size_t)gm * CDIM + nh * HDIM + ci];
            }
        } else { // MODE 2
            const int gm = mBase + r;
            const int b = gm >> 5, t = gm & 31;
            #pragma unroll
            for (int u = 0; u < 4; u++) {
                const int kg = kBase + kq * 4 + u;
                const int nh = kg >> 6;
                const int row = gidx[(b * NHEAD + nh) * TSEL + t];
                As[kq * 4 + u][r] = A[((size_t)(b * NTOK + row)) * CDIM + kg];
            }
        }
        // ---- stage W tile (64 out-cols x 16 k) transposed into Bs[k][col]
        {
            const float4 wv = *reinterpret_cast<const float4*>(
                &W[(size_t)(nBase + r) * K + kBase + kq * 4]);
            Bs[kq * 4 + 0][r] = wv.x; Bs[kq * 4 + 1][r] = wv.y;
            Bs[kq * 4 + 2][r] = wv.z; Bs[kq * 4 + 3][r] = wv.w;
        }
        __syncthreads();

        // tile-local accumulator (chunked summation: closer to numpy's
        // pairwise order -> less drift on the top-k decision path)
        float tacc[4][4] = {};
        #pragma unroll
        for (int kk = 0; kk < 16; kk++) {
            const float4 a4 = *reinterpret_cast<const float4*>(&As[kk][ty * 4]);
            const float4 b4 = *reinterpret_cast<const float4*>(&Bs[kk][tx * 4]);
            const float av[4] = {a4.x, a4.y, a4.z, a4.w};
            const float bv[4] = {b4.x, b4.y, b4.z, b4.w};
            #pragma unroll
            for (int i = 0; i < 4; i++)
                #pragma unroll
                for (int j = 0; j < 4; j++)
                    tacc[i][j] += av[i] * bv[j];
        }
        #pragma unroll
        for (int i = 0; i < 4; i++)
            #pragma unroll
            for (int j = 0; j < 4; j++)
                acc[i][j] += tacc[i][j];
    }

    #pragma unroll
    for (int i = 0; i < 4; i++) {
        const int gm = mBase + ty * 4 + i;
        const int gn = nBase + tx * 4;
        float4 o;
        o.x = acc[i][0] + bias[gn + 0];
        o.y = acc[i][1] + bias[gn + 1];
        o.z = acc[i][2] + bias[gn + 2];
        o.w = acc[i][3] + bias[gn + 3];
        *reinterpret_cast<float4*>(&C[(size_t)gm * Nout + gn]) = o;
    }
}

// ---------------------------------------------------------------------------
// Per (b, nh): channel top-32 (cidx) and spatial top-32 (p), both ascending.
// Rank-based selection reproduces lax.top_k tie-breaking (lower index wins)
// and the subsequent jnp.sort for free.
// ---------------------------------------------------------------------------
__global__ __launch_bounds__(64) void topk_kernel(
    const float* __restrict__ q, const float* __restrict__ Wc,
    const float* __restrict__ bc, int* __restrict__ cidx, int* __restrict__ p)
{
    const int blk = blockIdx.x;
    const int b = blk / NHEAD, nh = blk % NHEAD;
    const int tid = threadIdx.x; // 64 threads = 1 wave

    __shared__ float chmean[64], chmax[64], rs[NTOK], logits[64];

    const float* qbase = q + (size_t)(b * NTOK) * CDIM + nh * HDIM;
    float sum = 0.f, mx = -INFINITY;
    for (int n = 0; n < NTOK; n++) {
        const float v = qbase[(size_t)n * CDIM + tid];
        sum += v;
        mx = fmaxf(mx, v);
        // wave-wide sum of v -> row sum (pairwise tree)
        float t = v;
        #pragma unroll
        for (int off = 32; off; off >>= 1) t += __shfl_xor(t, off);
        if (tid == 0) rs[n] = t * (1.0f / 64.0f);
    }
    chmean[tid] = sum * (1.0f / 49.0f);
    chmax[tid] = mx;
    __syncthreads();

    // logits[j] = gelu( feat . Wc[j,:] + bc[j] );  feat = [chmean, chmax]
    float accv = bc[tid];
    const float* wrow = Wc + tid * 128;
    for (int c = 0; c < 64; c++) accv += chmean[c] * wrow[c];
    for (int c = 0; c < 64; c++) accv += chmax[c] * wrow[64 + c];
    const float g = 0.5f * accv * (1.0f + erff(accv * 0.70710678118654752f));
    logits[tid] = g; // softmax is monotone -> rank on gelu output directly
    __syncthreads();

    // channel rank among 64
    int rank = 0;
    for (int kk = 0; kk < 64; kk++) {
        const float o = logits[kk];
        rank += (o > g) || (o == g && kk < tid);
    }
    const bool sel = rank < HD2;
    const unsigned long long mask = __ballot(sel);
    if (sel) {
        const int pos = __popcll(mask & ((1ull << tid) - 1ull));
        cidx[blk * HD2 + pos] = tid;
    }
    __syncthreads();

    // spatial rank among 49 row-means
    if (tid < NTOK) {
        const float rv = rs[tid];
        int rank2 = 0;
        for (int m = 0; m < NTOK; m++) {
            const float o = rs[m];
            rank2 += (o > rv) || (o == rv && m < tid);
        }
        const bool sel2 = rank2 < TSEL;
        const unsigned long long mask2 = __ballot(sel2);
        if (sel2) {
            const int pos = __popcll(mask2 & ((1ull << tid) - 1ull));
            p[blk * TSEL + pos] = tid;
        }
    }
}

// ---------------------------------------------------------------------------
// Per (b, nh): attn (49x32) = kh @ qal^T + bias, softmax+gate, o = a@vh*gate.
// Writes o into obuf (aliases q buffer: each block only touches its own
// (b, head-column) slice, and all q reads happen before the writes).
// ---------------------------------------------------------------------------
__global__ __launch_bounds__(64) void attn_kernel(
    const float* __restrict__ q, const float* __restrict__ k,
    const float* __restrict__ v, const float* __restrict__ bias_table,
    const int* __restrict__ cidx, const int* __restrict__ p,
    float* __restrict__ obuf)
{
    const int blk = blockIdx.x;
    const int b = blk / NHEAD, nh = blk % NHEAD;
    const int tid = threadIdx.x; // 64 threads

    __shared__ int cI[TSEL], pI[TSEL];
    __shared__ float qal[TSEL][33];
    __shared__ float kh[NTOK][33];
    __shared__ float attnS[NTOK][33];
    __shared__ float gateS[NTOK];
    __shared__ float vs[TSEL][65];

    if (tid < TSEL) {
        cI[tid] = cidx[blk * HD2 + tid];
        pI[tid] = p[blk * TSEL + tid];
    }
    __syncthreads();

    for (int idx = tid; idx < TSEL * HD2; idx += 64) {
        const int t = idx >> 5, j = idx & 31;
        qal[t][j] = q[((size_t)(b * NTOK + pI[t])) * CDIM + nh * HDIM + cI[j]] * SCALE_Q;
    }
    for (int idx = tid; idx < NTOK * HD2; idx += 64) {
        const int i = idx >> 5, j = idx & 31;
        kh[i][j] = k[((size_t)(b * NTOK + i)) * C2DIM + nh * HD2 + j];
    }
    for (int idx = tid; idx < TSEL * HDIM; idx += 64) {
        const int t = idx >> 6, d = idx & 63;
        vs[t][d] = v[((size_t)(b * TSEL + t)) * CDIM + nh * HDIM + d];
    }
    __syncthreads();

    // attn logits + rel-pos bias
    {
        const int t = tid & 31;
        const int pt = pI[t];
        const int pti = pt / 7, ptj = pt % 7;
        for (int i = tid >> 5; i < NTOK; i += 2) {
            const int ri = i / 7 - pti + 6;
            const int rj = i % 7 - ptj + 6;
            float a = bias_table[(ri * 13 + rj) * NHEAD + nh];
            #pragma unroll
            for (int j = 0; j < HD2; j++) a += kh[i][j] * qal[t][j];
            attnS[i][t] = a;
        }
    }
    __syncthreads();

    // per-row softmax over t, and gate = sigmoid(mean)
    if (tid < NTOK) {
        float m = -INFINITY, tot = 0.f;
        for (int tt = 0; tt < TSEL; tt++) {
            const float xv = attnS[tid][tt];
            tot += xv;
            m = fmaxf(m, xv);
        }
        float s = 0.f;
        for (int tt = 0; tt < TSEL; tt++) s += expf(attnS[tid][tt] - m);
        const float inv = 1.0f / s;
        for (int tt = 0; tt < TSEL; tt++)
            attnS[tid][tt] = expf(attnS[tid][tt] - m) * inv;
        gateS[tid] = 1.0f / (1.0f + expf(-tot * (1.0f / 32.0f)));
    }
    __syncthreads();

    // o[i][d] = gate[i] * sum_t a[i][t] * vs[t][d];  thread owns column d=tid
    for (int i = 0; i < NTOK; i++) {
        float acc = 0.f;
        #pragma unroll
        for (int tt = 0; tt < TSEL; tt++) acc += attnS[i][tt] * vs[tt][tid];
        obuf[((size_t)(b * NTOK + i)) * CDIM + nh * HDIM + tid] = acc * gateS[i];
    }
}

// ---------------------------------------------------------------------------
extern "C" void kernel_launch(void* const* d_in, const int* in_sizes, int n_in,
                              void* d_out, int out_size, void* d_ws, size_t ws_size,
                              hipStream_t stream)
{
    const float* x = (const float*)d_in[0];
    const float* Wq = (const float*)d_in[1];
    const float* bq = (const float*)d_in[2];
    const float* Wk = (const float*)d_in[3];
    const float* bk = (const float*)d_in[4];
    const float* Wv = (const float*)d_in[5];
    const float* bv = (const float*)d_in[6];
    const float* Wp = (const float*)d_in[7];
    const float* bp = (const float*)d_in[8];
    const float* Wc = (const float*)d_in[9];
    const float* bc = (const float*)d_in[10];
    const float* bias_table = (const float*)d_in[11];
    float* out = (float*)d_out;

    const size_t qBytes = (size_t)BATCH * NTOK * CDIM * 4;  // 308 MB (q, later o)
    const size_t kBytes = (size_t)BATCH * NTOK * C2DIM * 4; // 154 MB
    const size_t vBytes = (size_t)BATCH * TSEL * CDIM * 4;  // 201 MB
    const size_t iBytes = (size_t)BATCH * NHEAD * HD2 * 4;  //   3 MB each

    char* wsp = (char*)d_ws;
    float* qbuf = (float*)wsp; wsp += qBytes;
    float* kbuf = (float*)wsp; wsp += kBytes;
    float* vbuf = (float*)wsp; wsp += vBytes;
    int* cidx = (int*)wsp; wsp += iBytes;
    int* pidx = (int*)wsp; wsp += iBytes;
    if ((size_t)(wsp - (char*)d_ws) > ws_size) return; // ws too small -> out stays 0

    const int M = BATCH * NTOK; // 100352 (divisible by 64)
    const dim3 blk(256);

    // 1) q = x @ Wq^T + bq
    gemm_kernel<0><<<dim3(M / 64, CDIM / 64), blk, 0, stream>>>(
        x, Wq, bq, qbuf, M, CDIM, CDIM, nullptr);
    // 2) top-k channel + spatial selections
    topk_kernel<<<BATCH * NHEAD, 64, 0, stream>>>(qbuf, Wc, bc, cidx, pidx);
    // 3) k = gather_ch(q) @ Wk^T + bk
    gemm_kernel<1><<<dim3(M / 64, C2DIM / 64), blk, 0, stream>>>(
        qbuf, Wk, bk, kbuf, M, C2DIM, C2DIM, cidx);
    // 4) v = gather_tok(q) @ Wv^T + bv
    gemm_kernel<2><<<dim3((BATCH * TSEL) / 64, CDIM / 64), blk, 0, stream>>>(
        qbuf, Wv, bv, vbuf, BATCH * TSEL, CDIM, CDIM, pidx);
    // 5) attention (writes o into qbuf — q is dead afterwards)
    attn_kernel<<<BATCH * NHEAD, 64, 0, stream>>>(
        qbuf, kbuf, vbuf, bias_table, cidx, pidx, qbuf);
    // 6) out = o @ Wp^T + bp
    gemm_kernel<0><<<dim3(M / 64, CDIM / 64), blk, 0, stream>>>(
        qbuf, Wp, bp, out, M, CDIM, CDIM, nullptr);
}

// Round 4
// 2391.348 us; speedup vs baseline: 2.3335x; 2.3335x over previous
//
#include <hip/hip_runtime.h>
#include <cmath>

#define NHEAD 12
#define NTOK 49
#define CDIM 768
#define C2DIM 384
#define HDIM 64
#define HD2 32
#define TSEL 32
#define BATCH 2048
#define MROWS (BATCH * NTOK)   // 100352
#define MVROWS (BATCH * TSEL)  // 65536
constexpr float SCALE_Q = 0.125f; // 64^-0.5

typedef _Float16 f16x8 __attribute__((ext_vector_type(8)));
typedef float f32x4 __attribute__((ext_vector_type(4)));

// fp16 2-limb split: x == hi + lo + O(2^-24 x)  (Sterbenz-exact residual path)
__device__ __forceinline__ void split8(const float* v, f16x8& hi, f16x8& lo) {
    #pragma unroll
    for (int u = 0; u < 8; ++u) {
        const _Float16 h = (_Float16)v[u];
        hi[u] = h;
        lo[u] = (_Float16)(v[u] - (float)h);
    }
}
__device__ __forceinline__ void round8h(const float* v, f16x8& h) {
    #pragma unroll
    for (int u = 0; u < 8; ++u) h[u] = (_Float16)v[u];
}
// padded granule index: conflict-free ds_write_b128 AND ds_read_b128
#define GI(g) ((g) + ((g) >> 7))

// ---------------------------------------------------------------------------
// Split-fp16 GEMM from fp32 inputs: C[M,N] = A[M,K] @ W[N,K]^T + bias
// hi/lo split in-register; 3 MFMA products => fp32-class precision.
// 128x128 tile, BK=32, 4 waves.
// ---------------------------------------------------------------------------
__global__ __launch_bounds__(256) void gemm_split_kernel(
    const float* __restrict__ A, const float* __restrict__ W,
    const float* __restrict__ bias, float* __restrict__ C,
    int M, int N, int K)
{
    __shared__ f16x8 AhiS[516], AloS[516], BhiS[516], BloS[516];
    const int tid = threadIdx.x;
    const int lane = tid & 63, wid = tid >> 6;
    const int wr = wid >> 1, wc = wid & 1;
    const int mBase = blockIdx.x * 128, nBase = blockIdx.y * 128;
    const int rsub = tid >> 2, kc = tid & 3;

    f32x4 acc[4][4] = {};

    for (int kt = 0; kt < K; kt += 32) {
        __syncthreads();
        #pragma unroll
        for (int pass = 0; pass < 2; ++pass) {
            const int row = rsub + pass * 64;
            const int g = kc * 128 + row;
            const int gi = GI(g);
            {
                const float* ap = &A[(size_t)(mBase + row) * K + kt + kc * 8];
                float av[8];
                *reinterpret_cast<float4*>(&av[0]) = *reinterpret_cast<const float4*>(ap);
                *reinterpret_cast<float4*>(&av[4]) = *reinterpret_cast<const float4*>(ap + 4);
                f16x8 h, l; split8(av, h, l);
                AhiS[gi] = h; AloS[gi] = l;
            }
            {
                const float* wp = &W[(size_t)(nBase + row) * K + kt + kc * 8];
                float wv[8];
                *reinterpret_cast<float4*>(&wv[0]) = *reinterpret_cast<const float4*>(wp);
                *reinterpret_cast<float4*>(&wv[4]) = *reinterpret_cast<const float4*>(wp + 4);
                f16x8 h, l; split8(wv, h, l);
                BhiS[gi] = h; BloS[gi] = l;
            }
        }
        __syncthreads();

        const int ksl = (lane >> 4) << 7;
        const int rl = lane & 15;
        f16x8 ah[4], al[4], bh[4], bl[4];
        #pragma unroll
        for (int f = 0; f < 4; ++f) {
            ah[f] = AhiS[GI(ksl + wr * 64 + f * 16 + rl)];
            al[f] = AloS[GI(ksl + wr * 64 + f * 16 + rl)];
            bh[f] = BhiS[GI(ksl + wc * 64 + f * 16 + rl)];
            bl[f] = BloS[GI(ksl + wc * 64 + f * 16 + rl)];
        }
        #pragma unroll
        for (int i = 0; i < 4; ++i)
            #pragma unroll
            for (int j = 0; j < 4; ++j) {
                acc[i][j] = __builtin_amdgcn_mfma_f32_16x16x32_f16(ah[i], bh[j], acc[i][j], 0, 0, 0);
                acc[i][j] = __builtin_amdgcn_mfma_f32_16x16x32_f16(ah[i], bl[j], acc[i][j], 0, 0, 0);
                acc[i][j] = __builtin_amdgcn_mfma_f32_16x16x32_f16(al[i], bh[j], acc[i][j], 0, 0, 0);
            }
    }

    #pragma unroll
    for (int i = 0; i < 4; ++i) {
        const int rbase = mBase + wr * 64 + i * 16 + ((lane >> 4) << 2);
        #pragma unroll
        for (int j = 0; j < 4; ++j) {
            const int col = nBase + wc * 64 + j * 16 + (lane & 15);
            const float bv = bias[col];
            #pragma unroll
            for (int r = 0; r < 4; ++r)
                C[(size_t)(rbase + r) * N + col] = acc[i][j][r] + bv;
        }
    }
}

// ---------------------------------------------------------------------------
// k GEMM: plain fp16, channel-gathered A from fp32 q, Wk rounded in-register.
// k error attenuated through softmax; fp16 storage (err 8x below bf16).
// M=100352, N=K=384.
// ---------------------------------------------------------------------------
__global__ __launch_bounds__(256) void gemm_k_kernel(
    const float* __restrict__ Q, const float* __restrict__ Wk,
    const float* __restrict__ bias, _Float16* __restrict__ Ck,
    const int* __restrict__ cidx)
{
    const int N = C2DIM, K = C2DIM;
    __shared__ f16x8 AS[516], BS[516];
    const int tid = threadIdx.x;
    const int lane = tid & 63, wid = tid >> 6;
    const int wr = wid >> 1, wc = wid & 1;
    const int mBase = blockIdx.x * 128, nBase = blockIdx.y * 128;
    const int rsub = tid >> 2, kc = tid & 3;

    f32x4 acc[4][4] = {};

    for (int kt = 0; kt < K; kt += 32) {
        const int nh = kt >> 5; // head for this whole k-tile
        __syncthreads();
        #pragma unroll
        for (int pass = 0; pass < 2; ++pass) {
            const int row = rsub + pass * 64;
            const int g = kc * 128 + row;
            const int gi = GI(g);
            {
                const int gm = mBase + row;
                const int b = gm / NTOK;
                const int* cp = &cidx[(b * NHEAD + nh) * HD2 + kc * 8];
                const int4 c0 = *reinterpret_cast<const int4*>(cp);
                const int4 c1 = *reinterpret_cast<const int4*>(cp + 4);
                const float* qp = &Q[(size_t)gm * CDIM + nh * HDIM];
                float av[8];
                av[0] = qp[c0.x]; av[1] = qp[c0.y]; av[2] = qp[c0.z]; av[3] = qp[c0.w];
                av[4] = qp[c1.x]; av[5] = qp[c1.y]; av[6] = qp[c1.z]; av[7] = qp[c1.w];
                f16x8 h; round8h(av, h);
                AS[gi] = h;
            }
            {
                const float* wp = &Wk[(size_t)(nBase + row) * K + kt + kc * 8];
                float wv[8];
                *reinterpret_cast<float4*>(&wv[0]) = *reinterpret_cast<const float4*>(wp);
                *reinterpret_cast<float4*>(&wv[4]) = *reinterpret_cast<const float4*>(wp + 4);
                f16x8 h; round8h(wv, h);
                BS[gi] = h;
            }
        }
        __syncthreads();

        const int ksl = (lane >> 4) << 7;
        const int rl = lane & 15;
        f16x8 af[4], bf[4];
        #pragma unroll
        for (int f = 0; f < 4; ++f) {
            af[f] = AS[GI(ksl + wr * 64 + f * 16 + rl)];
            bf[f] = BS[GI(ksl + wc * 64 + f * 16 + rl)];
        }
        #pragma unroll
        for (int i = 0; i < 4; ++i)
            #pragma unroll
            for (int j = 0; j < 4; ++j)
                acc[i][j] = __builtin_amdgcn_mfma_f32_16x16x32_f16(af[i], bf[j], acc[i][j], 0, 0, 0);
    }

    #pragma unroll
    for (int i = 0; i < 4; ++i) {
        const int rbase = mBase + wr * 64 + i * 16 + ((lane >> 4) << 2);
        #pragma unroll
        for (int j = 0; j < 4; ++j) {
            const int col = nBase + wc * 64 + j * 16 + (lane & 15);
            const float bv = bias[col];
            #pragma unroll
            for (int r = 0; r < 4; ++r)
                Ck[(size_t)(rbase + r) * N + col] = (_Float16)(acc[i][j][r] + bv);
        }
    }
}

// ---------------------------------------------------------------------------
// v GEMM: split fp16x3, token-gathered A from fp32 q.  fp32 output.
// M=65536, N=K=768.
// ---------------------------------------------------------------------------
__global__ __launch_bounds__(256) void gemm_v_kernel(
    const float* __restrict__ Q, const float* __restrict__ Wv,
    const float* __restrict__ bias, float* __restrict__ C,
    const int* __restrict__ pidx)
{
    const int N = CDIM, K = CDIM;
    __shared__ f16x8 AhiS[516], AloS[516], BhiS[516], BloS[516];
    const int tid = threadIdx.x;
    const int lane = tid & 63, wid = tid >> 6;
    const int wr = wid >> 1, wc = wid & 1;
    const int mBase = blockIdx.x * 128, nBase = blockIdx.y * 128;
    const int rsub = tid >> 2, kc = tid & 3;

    f32x4 acc[4][4] = {};

    for (int kt = 0; kt < K; kt += 32) {
        const int nh = kt >> 6; // head owning this k-tile (BK=32 never straddles)
        __syncthreads();
        #pragma unroll
        for (int pass = 0; pass < 2; ++pass) {
            const int row = rsub + pass * 64;
            const int g = kc * 128 + row;
            const int gi = GI(g);
            {
                const int gm = mBase + row;
                const int b = gm >> 5, t = gm & 31;
                const int row2 = pidx[(b * NHEAD + nh) * TSEL + t];
                const float* qp = &Q[(size_t)(b * NTOK + row2) * CDIM + kt + kc * 8];
                float av[8];
                *reinterpret_cast<float4*>(&av[0]) = *reinterpret_cast<const float4*>(qp);
                *reinterpret_cast<float4*>(&av[4]) = *reinterpret_cast<const float4*>(qp + 4);
                f16x8 h, l; split8(av, h, l);
                AhiS[gi] = h; AloS[gi] = l;
            }
            {
                const float* wp = &Wv[(size_t)(nBase + row) * K + kt + kc * 8];
                float wv[8];
                *reinterpret_cast<float4*>(&wv[0]) = *reinterpret_cast<const float4*>(wp);
                *reinterpret_cast<float4*>(&wv[4]) = *reinterpret_cast<const float4*>(wp + 4);
                f16x8 h, l; split8(wv, h, l);
                BhiS[gi] = h; BloS[gi] = l;
            }
        }
        __syncthreads();

        const int ksl = (lane >> 4) << 7;
        const int rl = lane & 15;
        f16x8 ah[4], al[4], bh[4], bl[4];
        #pragma unroll
        for (int f = 0; f < 4; ++f) {
            ah[f] = AhiS[GI(ksl + wr * 64 + f * 16 + rl)];
            al[f] = AloS[GI(ksl + wr * 64 + f * 16 + rl)];
            bh[f] = BhiS[GI(ksl + wc * 64 + f * 16 + rl)];
            bl[f] = BloS[GI(ksl + wc * 64 + f * 16 + rl)];
        }
        #pragma unroll
        for (int i = 0; i < 4; ++i)
            #pragma unroll
            for (int j = 0; j < 4; ++j) {
                acc[i][j] = __builtin_amdgcn_mfma_f32_16x16x32_f16(ah[i], bh[j], acc[i][j], 0, 0, 0);
                acc[i][j] = __builtin_amdgcn_mfma_f32_16x16x32_f16(ah[i], bl[j], acc[i][j], 0, 0, 0);
                acc[i][j] = __builtin_amdgcn_mfma_f32_16x16x32_f16(al[i], bh[j], acc[i][j], 0, 0, 0);
            }
    }

    #pragma unroll
    for (int i = 0; i < 4; ++i) {
        const int rbase = mBase + wr * 64 + i * 16 + ((lane >> 4) << 2);
        #pragma unroll
        for (int j = 0; j < 4; ++j) {
            const int col = nBase + wc * 64 + j * 16 + (lane & 15);
            const float bv = bias[col];
            #pragma unroll
            for (int r = 0; r < 4; ++r)
                C[(size_t)(rbase + r) * N + col] = acc[i][j][r] + bv;
        }
    }
}

// ---------------------------------------------------------------------------
// Per (b, nh): channel top-32 and spatial top-32 from fp32-class q.
// Rank-based selection == lax.top_k tie-break + jnp.sort. (R1's passing code)
// ---------------------------------------------------------------------------
__global__ __launch_bounds__(64) void topk_kernel(
    const float* __restrict__ q, const float* __restrict__ Wc,
    const float* __restrict__ bc, int* __restrict__ cidx, int* __restrict__ p)
{
    const int blk = blockIdx.x;
    const int b = blk / NHEAD, nh = blk % NHEAD;
    const int tid = threadIdx.x; // 64 threads = 1 wave

    __shared__ float chmean[64], chmax[64], rs[NTOK], logits[64];

    const float* qbase = q + (size_t)(b * NTOK) * CDIM + nh * HDIM;
    float sum = 0.f, mx = -INFINITY;
    for (int n = 0; n < NTOK; n++) {
        const float v = qbase[(size_t)n * CDIM + tid];
        sum += v;
        mx = fmaxf(mx, v);
        float t = v;
        #pragma unroll
        for (int off = 32; off; off >>= 1) t += __shfl_xor(t, off);
        if (tid == 0) rs[n] = t * (1.0f / 64.0f);
    }
    chmean[tid] = sum * (1.0f / 49.0f);
    chmax[tid] = mx;
    __syncthreads();

    float accv = bc[tid];
    const float* wrow = Wc + tid * 128;
    for (int c = 0; c < 64; c++) accv += chmean[c] * wrow[c];
    for (int c = 0; c < 64; c++) accv += chmax[c] * wrow[64 + c];
    const float g = 0.5f * accv * (1.0f + erff(accv * 0.70710678118654752f));
    logits[tid] = g;
    __syncthreads();

    int rank = 0;
    for (int kk = 0; kk < 64; kk++) {
        const float o = logits[kk];
        rank += (o > g) || (o == g && kk < tid);
    }
    const bool sel = rank < HD2;
    const unsigned long long mask = __ballot(sel);
    if (sel) {
        const int pos = __popcll(mask & ((1ull << tid) - 1ull));
        cidx[blk * HD2 + pos] = tid;
    }
    __syncthreads();

    if (tid < NTOK) {
        const float rv = rs[tid];
        int rank2 = 0;
        for (int m = 0; m < NTOK; m++) {
            const float o = rs[m];
            rank2 += (o > rv) || (o == rv && m < tid);
        }
        const bool sel2 = rank2 < TSEL;
        const unsigned long long mask2 = __ballot(sel2);
        if (sel2) {
            const int pos = __popcll(mask2 & ((1ull << tid) - 1ull));
            p[blk * TSEL + pos] = tid;
        }
    }
}

// ---------------------------------------------------------------------------
// Per (b, nh) attention; k fp16, v fp32, math fp32, o written into qbuf.
// ---------------------------------------------------------------------------
__global__ __launch_bounds__(64) void attn_kernel(
    const float* __restrict__ q, const _Float16* __restrict__ k,
    const float* __restrict__ v, const float* __restrict__ bias_table,
    const int* __restrict__ cidx, const int* __restrict__ p,
    float* __restrict__ obuf)
{
    const int blk = blockIdx.x;
    const int b = blk / NHEAD, nh = blk % NHEAD;
    const int tid = threadIdx.x;

    __shared__ int cI[TSEL], pI[TSEL];
    __shared__ float qal[TSEL][33];
    __shared__ float kh[NTOK][33];
    __shared__ float attnS[NTOK][33];
    __shared__ float gateS[NTOK];
    __shared__ float vs[TSEL][65];

    if (tid < TSEL) {
        cI[tid] = cidx[blk * HD2 + tid];
        pI[tid] = p[blk * TSEL + tid];
    }
    __syncthreads();

    for (int idx = tid; idx < TSEL * HD2; idx += 64) {
        const int t = idx >> 5, j = idx & 31;
        qal[t][j] = q[((size_t)(b * NTOK + pI[t])) * CDIM + nh * HDIM + cI[j]] * SCALE_Q;
    }
    for (int idx = tid; idx < NTOK * HD2; idx += 64) {
        const int i = idx >> 5, j = idx & 31;
        kh[i][j] = (float)k[((size_t)(b * NTOK + i)) * C2DIM + nh * HD2 + j];
    }
    for (int idx = tid; idx < TSEL * HDIM; idx += 64) {
        const int t = idx >> 6, d = idx & 63;
        vs[t][d] = v[((size_t)(b * TSEL + t)) * CDIM + nh * HDIM + d];
    }
    __syncthreads();

    {
        const int t = tid & 31;
        const int pt = pI[t];
        const int pti = pt / 7, ptj = pt % 7;
        for (int i = tid >> 5; i < NTOK; i += 2) {
            const int ri = i / 7 - pti + 6;
            const int rj = i % 7 - ptj + 6;
            float a = bias_table[(ri * 13 + rj) * NHEAD + nh];
            #pragma unroll
            for (int j = 0; j < HD2; j++) a += kh[i][j] * qal[t][j];
            attnS[i][t] = a;
        }
    }
    __syncthreads();

    if (tid < NTOK) {
        float m = -INFINITY, tot = 0.f;
        for (int tt = 0; tt < TSEL; tt++) {
            const float xv = attnS[tid][tt];
            tot += xv;
            m = fmaxf(m, xv);
        }
        float s = 0.f;
        for (int tt = 0; tt < TSEL; tt++) s += expf(attnS[tid][tt] - m);
        const float inv = 1.0f / s;
        for (int tt = 0; tt < TSEL; tt++)
            attnS[tid][tt] = expf(attnS[tid][tt] - m) * inv;
        gateS[tid] = 1.0f / (1.0f + expf(-tot * (1.0f / 32.0f)));
    }
    __syncthreads();

    for (int i = 0; i < NTOK; i++) {
        float acc = 0.f;
        #pragma unroll
        for (int tt = 0; tt < TSEL; tt++) acc += attnS[i][tt] * vs[tt][tid];
        obuf[((size_t)(b * NTOK + i)) * CDIM + nh * HDIM + tid] = acc * gateS[i];
    }
}

// ---------------------------------------------------------------------------
extern "C" void kernel_launch(void* const* d_in, const int* in_sizes, int n_in,
                              void* d_out, int out_size, void* d_ws, size_t ws_size,
                              hipStream_t stream)
{
    const float* x = (const float*)d_in[0];
    const float* Wq = (const float*)d_in[1];
    const float* bq = (const float*)d_in[2];
    const float* Wk = (const float*)d_in[3];
    const float* bk = (const float*)d_in[4];
    const float* Wv = (const float*)d_in[5];
    const float* bv = (const float*)d_in[6];
    const float* Wp = (const float*)d_in[7];
    const float* bp = (const float*)d_in[8];
    const float* Wc = (const float*)d_in[9];
    const float* bc = (const float*)d_in[10];
    const float* bias_table = (const float*)d_in[11];
    float* out = (float*)d_out;

    const size_t NQ = (size_t)MROWS * CDIM;
    char* wsp = (char*)d_ws;
    auto alloc = [&](size_t bytes) -> void* {
        void* pp = (void*)wsp;
        wsp += (bytes + 255) & ~(size_t)255;
        return pp;
    };

    float* qbuf = (float*)alloc(NQ * 4);                               // 308 MB
    _Float16* kbf = (_Float16*)alloc((size_t)MROWS * C2DIM * 2);       // 77 MB
    float* vbuf = (float*)alloc((size_t)MVROWS * CDIM * 4);            // 201 MB
    int* cidx = (int*)alloc((size_t)BATCH * NHEAD * HD2 * 4);
    int* pidx = (int*)alloc((size_t)BATCH * NHEAD * TSEL * 4);
    if ((size_t)(wsp - (char*)d_ws) > ws_size) return;

    // 1) q = x @ Wq^T + bq   (fp16x3 split -> fp32-class precision)
    gemm_split_kernel<<<dim3(MROWS / 128, CDIM / 128), 256, 0, stream>>>(
        x, Wq, bq, qbuf, MROWS, CDIM, CDIM);

    // 2) selections (channel + spatial) from fp32-class q
    topk_kernel<<<BATCH * NHEAD, 64, 0, stream>>>(qbuf, Wc, bc, cidx, pidx);

    // 3) k = gather_ch(q) @ Wk^T + bk   (plain fp16 — softmax attenuates)
    gemm_k_kernel<<<dim3(MROWS / 128, C2DIM / 128), 256, 0, stream>>>(
        qbuf, Wk, bk, kbf, cidx);

    // 4) v = gather_tok(q) @ Wv^T + bv  (fp16x3 split -> fp32 out)
    gemm_v_kernel<<<dim3(MVROWS / 128, CDIM / 128), 256, 0, stream>>>(
        qbuf, Wv, bv, vbuf, pidx);

    // 5) attention -> o (into qbuf; per-block slice reads precede writes)
    attn_kernel<<<BATCH * NHEAD, 64, 0, stream>>>(
        qbuf, kbf, vbuf, bias_table, cidx, pidx, qbuf);

    // 6) out = o @ Wp^T + bp  (fp16x3 split)
    gemm_split_kernel<<<dim3(MROWS / 128, CDIM / 128), 256, 0, stream>>>(
        qbuf, Wp, bp, out, MROWS, CDIM, CDIM);
}

// Round 5
// 1817.611 us; speedup vs baseline: 3.0701x; 1.3157x over previous
//
#include <hip/hip_runtime.h>
#include <cmath>

#define NHEAD 12
#define NTOK 49
#define CDIM 768
#define C2DIM 384
#define HDIM 64
#define HD2 32
#define TSEL 32
#define BATCH 2048
#define MROWS (BATCH * NTOK)   // 100352
#define MVROWS (BATCH * TSEL)  // 65536
constexpr float SCALE_Q = 0.125f; // 64^-0.5

typedef _Float16 f16x8 __attribute__((ext_vector_type(8)));
typedef _Float16 f16x2 __attribute__((ext_vector_type(2)));
typedef float f32x4 __attribute__((ext_vector_type(4)));

// fp16 2-limb split: x == hi + lo + O(2^-24 x)  (Sterbenz-exact residual path)
__device__ __forceinline__ void split8(const float* v, f16x8& hi, f16x8& lo) {
    #pragma unroll
    for (int u = 0; u < 8; ++u) {
        const _Float16 h = (_Float16)v[u];
        hi[u] = h;
        lo[u] = (_Float16)(v[u] - (float)h);
    }
}
__device__ __forceinline__ void round8h(const float* v, f16x8& h) {
    #pragma unroll
    for (int u = 0; u < 8; ++u) h[u] = (_Float16)v[u];
}
// XOR-swizzled granule index: conflict-free ds_write_b128 AND ds_read_b128.
// g = ks*128 + row; gi%8 = (row%8) ^ (ks<<1) spreads the 4 ks-lanes of a row
// across distinct bank groups (write side), reads stay granule-consecutive.
#define GIX(g) ((g) ^ ((((g) >> 7) & 3) << 1))

// ---------------------------------------------------------------------------
// fp32 -> fp16 weight pre-convert (RNE, same rounding as in-register path)
// ---------------------------------------------------------------------------
__global__ __launch_bounds__(256) void wconv_kernel(
    const float* __restrict__ src, _Float16* __restrict__ dst, int n4)
{
    const int stride = gridDim.x * blockDim.x;
    for (int i = blockIdx.x * blockDim.x + threadIdx.x; i < n4; i += stride) {
        const float4 v = reinterpret_cast<const float4*>(src)[i];
        f16x2 a = {(_Float16)v.x, (_Float16)v.y};
        f16x2 b = {(_Float16)v.z, (_Float16)v.w};
        reinterpret_cast<f16x2*>(dst)[i * 2 + 0] = a;
        reinterpret_cast<f16x2*>(dst)[i * 2 + 1] = b;
    }
}

// ---------------------------------------------------------------------------
// Split-fp16 GEMM from fp32 inputs (q path only — feeds fragile top-k):
// C[M,N] = A[M,K] @ W[N,K]^T + bias, fp16x3 => fp32-class precision.
// 128x128 tile, BK=32, 4 waves.  Math identical to R4 (passing); only the
// LDS swizzle changed (no effect on summation order).
// ---------------------------------------------------------------------------
__global__ __launch_bounds__(256) void gemm_split_kernel(
    const float* __restrict__ A, const float* __restrict__ W,
    const float* __restrict__ bias, float* __restrict__ C,
    int M, int N, int K)
{
    __shared__ f16x8 AhiS[512], AloS[512], BhiS[512], BloS[512];
    const int tid = threadIdx.x;
    const int lane = tid & 63, wid = tid >> 6;
    const int wr = wid >> 1, wc = wid & 1;
    const int mBase = blockIdx.x * 128, nBase = blockIdx.y * 128;
    const int rsub = tid >> 2, kc = tid & 3;

    f32x4 acc[4][4] = {};

    for (int kt = 0; kt < K; kt += 32) {
        __syncthreads();
        #pragma unroll
        for (int pass = 0; pass < 2; ++pass) {
            const int row = rsub + pass * 64;
            const int g = kc * 128 + row;
            const int gi = GIX(g);
            {
                const float* ap = &A[(size_t)(mBase + row) * K + kt + kc * 8];
                float av[8];
                *reinterpret_cast<float4*>(&av[0]) = *reinterpret_cast<const float4*>(ap);
                *reinterpret_cast<float4*>(&av[4]) = *reinterpret_cast<const float4*>(ap + 4);
                f16x8 h, l; split8(av, h, l);
                AhiS[gi] = h; AloS[gi] = l;
            }
            {
                const float* wp = &W[(size_t)(nBase + row) * K + kt + kc * 8];
                float wv[8];
                *reinterpret_cast<float4*>(&wv[0]) = *reinterpret_cast<const float4*>(wp);
                *reinterpret_cast<float4*>(&wv[4]) = *reinterpret_cast<const float4*>(wp + 4);
                f16x8 h, l; split8(wv, h, l);
                BhiS[gi] = h; BloS[gi] = l;
            }
        }
        __syncthreads();

        const int ksl = (lane >> 4) << 7;
        const int rl = lane & 15;
        f16x8 ah[4], al[4], bh[4], bl[4];
        #pragma unroll
        for (int f = 0; f < 4; ++f) {
            ah[f] = AhiS[GIX(ksl + wr * 64 + f * 16 + rl)];
            al[f] = AloS[GIX(ksl + wr * 64 + f * 16 + rl)];
            bh[f] = BhiS[GIX(ksl + wc * 64 + f * 16 + rl)];
            bl[f] = BloS[GIX(ksl + wc * 64 + f * 16 + rl)];
        }
        #pragma unroll
        for (int i = 0; i < 4; ++i)
            #pragma unroll
            for (int j = 0; j < 4; ++j) {
                acc[i][j] = __builtin_amdgcn_mfma_f32_16x16x32_f16(ah[i], bh[j], acc[i][j], 0, 0, 0);
                acc[i][j] = __builtin_amdgcn_mfma_f32_16x16x32_f16(ah[i], bl[j], acc[i][j], 0, 0, 0);
                acc[i][j] = __builtin_amdgcn_mfma_f32_16x16x32_f16(al[i], bh[j], acc[i][j], 0, 0, 0);
            }
    }

    #pragma unroll
    for (int i = 0; i < 4; ++i) {
        const int rbase = mBase + wr * 64 + i * 16 + ((lane >> 4) << 2);
        #pragma unroll
        for (int j = 0; j < 4; ++j) {
            const int col = nBase + wc * 64 + j * 16 + (lane & 15);
            const float bv = bias[col];
            #pragma unroll
            for (int r = 0; r < 4; ++r)
                C[(size_t)(rbase + r) * N + col] = acc[i][j][r] + bv;
        }
    }
}

// ---------------------------------------------------------------------------
// Plain-fp16 GEMM (1 MFMA product), post-decision paths only.
// MODE 0: A = fp16 row-major (o buffer), fp32 output (final out + bias)
// MODE 1: A = channel-gather from fp32 q (cidx), fp16 output (k)
// MODE 2: A = token-gather rows from fp32 q (pidx), fp16 output (v)
// ---------------------------------------------------------------------------
template <int MODE>
__global__ __launch_bounds__(256) void gemm_f16_kernel(
    const void* __restrict__ Asrc, const _Float16* __restrict__ Bw,
    const float* __restrict__ bias, void* __restrict__ Cout,
    int M, int N, int K, const int* __restrict__ gidx)
{
    __shared__ f16x8 AS[512], BS[512];
    const int tid = threadIdx.x;
    const int lane = tid & 63, wid = tid >> 6;
    const int wr = wid >> 1, wc = wid & 1;
    const int mBase = blockIdx.x * 128, nBase = blockIdx.y * 128;
    const int rsub = tid >> 2, kc = tid & 3;

    f32x4 acc[4][4] = {};

    for (int kt = 0; kt < K; kt += 32) {
        __syncthreads();
        #pragma unroll
        for (int pass = 0; pass < 2; ++pass) {
            const int row = rsub + pass * 64;
            const int g = kc * 128 + row;
            const int gi = GIX(g);
            const int kg = kt + kc * 8;
            if (MODE == 0) {
                const _Float16* ap = (const _Float16*)Asrc;
                AS[gi] = *reinterpret_cast<const f16x8*>(
                    &ap[(size_t)(mBase + row) * K + kg]);
            } else if (MODE == 1) {
                const float* Q = (const float*)Asrc;
                const int gm = mBase + row;
                const int b = gm / NTOK;
                const int nh = kg >> 5;
                const int* cp = &gidx[(b * NHEAD + nh) * HD2 + (kg & 31)];
                const int4 c0 = *reinterpret_cast<const int4*>(cp);
                const int4 c1 = *reinterpret_cast<const int4*>(cp + 4);
                const float* qp = &Q[(size_t)gm * CDIM + nh * HDIM];
                float av[8];
                av[0] = qp[c0.x]; av[1] = qp[c0.y]; av[2] = qp[c0.z]; av[3] = qp[c0.w];
                av[4] = qp[c1.x]; av[5] = qp[c1.y]; av[6] = qp[c1.z]; av[7] = qp[c1.w];
                f16x8 h; round8h(av, h);
                AS[gi] = h;
            } else { // MODE 2
                const float* Q = (const float*)Asrc;
                const int gm = mBase + row;
                const int b = gm >> 5, t = gm & 31;
                const int nh = kg >> 6;
                const int row2 = gidx[(b * NHEAD + nh) * TSEL + t];
                const float* qp = &Q[(size_t)(b * NTOK + row2) * CDIM + kg];
                float av[8];
                *reinterpret_cast<float4*>(&av[0]) = *reinterpret_cast<const float4*>(qp);
                *reinterpret_cast<float4*>(&av[4]) = *reinterpret_cast<const float4*>(qp + 4);
                f16x8 h; round8h(av, h);
                AS[gi] = h;
            }
            BS[gi] = *reinterpret_cast<const f16x8*>(
                &Bw[(size_t)(nBase + row) * K + kg]);
        }
        __syncthreads();

        const int ksl = (lane >> 4) << 7;
        const int rl = lane & 15;
        f16x8 af[4], bf[4];
        #pragma unroll
        for (int f = 0; f < 4; ++f) {
            af[f] = AS[GIX(ksl + wr * 64 + f * 16 + rl)];
            bf[f] = BS[GIX(ksl + wc * 64 + f * 16 + rl)];
        }
        #pragma unroll
        for (int i = 0; i < 4; ++i)
            #pragma unroll
            for (int j = 0; j < 4; ++j)
                acc[i][j] = __builtin_amdgcn_mfma_f32_16x16x32_f16(af[i], bf[j], acc[i][j], 0, 0, 0);
    }

    #pragma unroll
    for (int i = 0; i < 4; ++i) {
        const int rbase = mBase + wr * 64 + i * 16 + ((lane >> 4) << 2);
        #pragma unroll
        for (int j = 0; j < 4; ++j) {
            const int col = nBase + wc * 64 + j * 16 + (lane & 15);
            const float bv = bias[col];
            #pragma unroll
            for (int r = 0; r < 4; ++r) {
                const float o = acc[i][j][r] + bv;
                if (MODE == 0)
                    ((float*)Cout)[(size_t)(rbase + r) * N + col] = o;
                else
                    ((_Float16*)Cout)[(size_t)(rbase + r) * N + col] = (_Float16)o;
            }
        }
    }
}

// ---------------------------------------------------------------------------
// Per (b, nh): channel top-32 and spatial top-32 from fp32-class q.
// Rank-based selection == lax.top_k tie-break + jnp.sort. (unchanged, passing)
// ---------------------------------------------------------------------------
__global__ __launch_bounds__(64) void topk_kernel(
    const float* __restrict__ q, const float* __restrict__ Wc,
    const float* __restrict__ bc, int* __restrict__ cidx, int* __restrict__ p)
{
    const int blk = blockIdx.x;
    const int b = blk / NHEAD, nh = blk % NHEAD;
    const int tid = threadIdx.x; // 64 threads = 1 wave

    __shared__ float chmean[64], chmax[64], rs[NTOK], logits[64];

    const float* qbase = q + (size_t)(b * NTOK) * CDIM + nh * HDIM;
    float sum = 0.f, mx = -INFINITY;
    for (int n = 0; n < NTOK; n++) {
        const float v = qbase[(size_t)n * CDIM + tid];
        sum += v;
        mx = fmaxf(mx, v);
        float t = v;
        #pragma unroll
        for (int off = 32; off; off >>= 1) t += __shfl_xor(t, off);
        if (tid == 0) rs[n] = t * (1.0f / 64.0f);
    }
    chmean[tid] = sum * (1.0f / 49.0f);
    chmax[tid] = mx;
    __syncthreads();

    float accv = bc[tid];
    const float* wrow = Wc + tid * 128;
    for (int c = 0; c < 64; c++) accv += chmean[c] * wrow[c];
    for (int c = 0; c < 64; c++) accv += chmax[c] * wrow[64 + c];
    const float g = 0.5f * accv * (1.0f + erff(accv * 0.70710678118654752f));
    logits[tid] = g;
    __syncthreads();

    int rank = 0;
    for (int kk = 0; kk < 64; kk++) {
        const float o = logits[kk];
        rank += (o > g) || (o == g && kk < tid);
    }
    const bool sel = rank < HD2;
    const unsigned long long mask = __ballot(sel);
    if (sel) {
        const int pos = __popcll(mask & ((1ull << tid) - 1ull));
        cidx[blk * HD2 + pos] = tid;
    }
    __syncthreads();

    if (tid < NTOK) {
        const float rv = rs[tid];
        int rank2 = 0;
        for (int m = 0; m < NTOK; m++) {
            const float o = rs[m];
            rank2 += (o > rv) || (o == rv && m < tid);
        }
        const bool sel2 = rank2 < TSEL;
        const unsigned long long mask2 = __ballot(sel2);
        if (sel2) {
            const int pos = __popcll(mask2 & ((1ull << tid) - 1ull));
            p[blk * TSEL + pos] = tid;
        }
    }
}

// ---------------------------------------------------------------------------
// Per (b, nh) attention; 128 threads (2 waves).  k fp16, v fp16, o fp16 out.
// fp32 math throughout (same numerics class as R4's passing kernel).
// ---------------------------------------------------------------------------
__global__ __launch_bounds__(128) void attn_kernel(
    const float* __restrict__ q, const _Float16* __restrict__ k,
    const _Float16* __restrict__ v, const float* __restrict__ bias_table,
    const int* __restrict__ cidx, const int* __restrict__ p,
    _Float16* __restrict__ obuf)
{
    const int blk = blockIdx.x;
    const int b = blk / NHEAD, nh = blk % NHEAD;
    const int tid = threadIdx.x;

    __shared__ int cI[TSEL], pI[TSEL];
    __shared__ float qal[TSEL][33];
    __shared__ float kh[NTOK][33];
    __shared__ float attnS[NTOK][33];
    __shared__ float gateS[NTOK];
    __shared__ float vs[TSEL][65];

    if (tid < TSEL) {
        cI[tid] = cidx[blk * HD2 + tid];
        pI[tid] = p[blk * TSEL + tid];
    }
    __syncthreads();

    // qal: 32x32 gathered fp32
    for (int idx = tid; idx < TSEL * HD2; idx += 128) {
        const int t = idx >> 5, j = idx & 31;
        qal[t][j] = q[((size_t)(b * NTOK + pI[t])) * CDIM + nh * HDIM + cI[j]] * SCALE_Q;
    }
    // kh: 49x32 from fp16 k
    for (int idx = tid; idx < NTOK * HD2; idx += 128) {
        const int i = idx >> 5, j = idx & 31;
        kh[i][j] = (float)k[((size_t)(b * NTOK + i)) * C2DIM + nh * HD2 + j];
    }
    // vs: 32x64 from fp16 v, 16B vector loads
    for (int idx = tid; idx < TSEL * 8; idx += 128) {
        const int t = idx >> 3, seg = idx & 7;
        const f16x8 vv = *reinterpret_cast<const f16x8*>(
            &v[((size_t)(b * TSEL + t)) * CDIM + nh * HDIM + seg * 8]);
        #pragma unroll
        for (int u = 0; u < 8; ++u) vs[t][seg * 8 + u] = (float)vv[u];
    }
    __syncthreads();

    // QK^T + rel-pos bias: thread (quarter = tid>>5 -> rows, t = tid&31 -> col)
    {
        const int t = tid & 31;
        const int pt = pI[t];
        const int pti = pt / 7, ptj = pt % 7;
        for (int i = tid >> 5; i < NTOK; i += 4) {
            const int ri = i / 7 - pti + 6;
            const int rj = i % 7 - ptj + 6;
            float a = bias_table[(ri * 13 + rj) * NHEAD + nh];
            #pragma unroll
            for (int j = 0; j < HD2; j++) a += kh[i][j] * qal[t][j];
            attnS[i][t] = a;
        }
    }
    __syncthreads();

    // per-row softmax + gate
    if (tid < NTOK) {
        float m = -INFINITY, tot = 0.f;
        for (int tt = 0; tt < TSEL; tt++) {
            const float xv = attnS[tid][tt];
            tot += xv;
            m = fmaxf(m, xv);
        }
        float s = 0.f;
        for (int tt = 0; tt < TSEL; tt++) s += expf(attnS[tid][tt] - m);
        const float inv = 1.0f / s;
        for (int tt = 0; tt < TSEL; tt++)
            attnS[tid][tt] = expf(attnS[tid][tt] - m) * inv;
        gateS[tid] = 1.0f / (1.0f + expf(-tot * (1.0f / 32.0f)));
    }
    __syncthreads();

    // PV: thread owns 2 adjacent d columns; quarter-strided rows; fp16x2 store
    {
        const int d2 = (tid & 31) * 2;
        for (int i = tid >> 5; i < NTOK; i += 4) {
            float a0 = 0.f, a1 = 0.f;
            #pragma unroll
            for (int tt = 0; tt < TSEL; tt++) {
                const float w = attnS[i][tt];
                a0 += w * vs[tt][d2];
                a1 += w * vs[tt][d2 + 1];
            }
            const float gg = gateS[i];
            f16x2 o2 = {(_Float16)(a0 * gg), (_Float16)(a1 * gg)};
            *reinterpret_cast<f16x2*>(
                &obuf[((size_t)(b * NTOK + i)) * CDIM + nh * HDIM + d2]) = o2;
        }
    }
}

// ---------------------------------------------------------------------------
extern "C" void kernel_launch(void* const* d_in, const int* in_sizes, int n_in,
                              void* d_out, int out_size, void* d_ws, size_t ws_size,
                              hipStream_t stream)
{
    const float* x = (const float*)d_in[0];
    const float* Wq = (const float*)d_in[1];
    const float* bq = (const float*)d_in[2];
    const float* Wk = (const float*)d_in[3];
    const float* bk = (const float*)d_in[4];
    const float* Wv = (const float*)d_in[5];
    const float* bv = (const float*)d_in[6];
    const float* Wp = (const float*)d_in[7];
    const float* bp = (const float*)d_in[8];
    const float* Wc = (const float*)d_in[9];
    const float* bc = (const float*)d_in[10];
    const float* bias_table = (const float*)d_in[11];
    float* out = (float*)d_out;

    const size_t NQ = (size_t)MROWS * CDIM;
    char* wsp = (char*)d_ws;
    auto alloc = [&](size_t bytes) -> void* {
        void* pp = (void*)wsp;
        wsp += (bytes + 255) & ~(size_t)255;
        return pp;
    };

    float* qbuf = (float*)alloc(NQ * 4);                           // 308 MB
    _Float16* kbf = (_Float16*)alloc((size_t)MROWS * C2DIM * 2);   // 77 MB
    _Float16* vbf = (_Float16*)alloc((size_t)MVROWS * CDIM * 2);   // 100 MB
    _Float16* obf = (_Float16*)alloc(NQ * 2);                      // 154 MB
    _Float16* wk16 = (_Float16*)alloc((size_t)C2DIM * C2DIM * 2);
    _Float16* wv16 = (_Float16*)alloc((size_t)CDIM * CDIM * 2);
    _Float16* wp16 = (_Float16*)alloc((size_t)CDIM * CDIM * 2);
    int* cidx = (int*)alloc((size_t)BATCH * NHEAD * HD2 * 4);
    int* pidx = (int*)alloc((size_t)BATCH * NHEAD * TSEL * 4);
    if ((size_t)(wsp - (char*)d_ws) > ws_size) return;

    // 0) pre-convert post-decision weights to fp16
    wconv_kernel<<<144, 256, 0, stream>>>(Wk, wk16, C2DIM * C2DIM / 4);
    wconv_kernel<<<256, 256, 0, stream>>>(Wv, wv16, CDIM * CDIM / 4);
    wconv_kernel<<<256, 256, 0, stream>>>(Wp, wp16, CDIM * CDIM / 4);

    // 1) q = x @ Wq^T + bq   (fp16x3 split -> fp32-class; feeds top-k)
    gemm_split_kernel<<<dim3(MROWS / 128, CDIM / 128), 256, 0, stream>>>(
        x, Wq, bq, qbuf, MROWS, CDIM, CDIM);

    // 2) selections (channel + spatial) from fp32-class q
    topk_kernel<<<BATCH * NHEAD, 64, 0, stream>>>(qbuf, Wc, bc, cidx, pidx);

    // 3) k = gather_ch(q) @ Wk^T + bk   (fp16, 1 product)
    gemm_f16_kernel<1><<<dim3(MROWS / 128, C2DIM / 128), 256, 0, stream>>>(
        qbuf, wk16, bk, kbf, MROWS, C2DIM, C2DIM, cidx);

    // 4) v = gather_tok(q) @ Wv^T + bv  (fp16, 1 product)
    gemm_f16_kernel<2><<<dim3(MVROWS / 128, CDIM / 128), 256, 0, stream>>>(
        qbuf, wv16, bv, vbf, MVROWS, CDIM, CDIM, pidx);

    // 5) attention -> o fp16
    attn_kernel<<<BATCH * NHEAD, 128, 0, stream>>>(
        qbuf, kbf, vbf, bias_table, cidx, pidx, obf);

    // 6) out = o @ Wp^T + bp  (fp16, 1 product, fp32 out)
    gemm_f16_kernel<0><<<dim3(MROWS / 128, CDIM / 128), 256, 0, stream>>>(
        obf, wp16, bp, out, MROWS, CDIM, CDIM, nullptr);
}

// Round 6
// 1785.495 us; speedup vs baseline: 3.1254x; 1.0180x over previous
//
#include <hip/hip_runtime.h>
#include <cmath>

#define NHEAD 12
#define NTOK 49
#define CDIM 768
#define C2DIM 384
#define HDIM 64
#define HD2 32
#define TSEL 32
#define BATCH 2048
#define MROWS (BATCH * NTOK)   // 100352
#define MVROWS (BATCH * TSEL)  // 65536
constexpr float SCALE_Q = 0.125f; // 64^-0.5

typedef _Float16 f16x8 __attribute__((ext_vector_type(8)));
typedef _Float16 f16x2 __attribute__((ext_vector_type(2)));
typedef float f32x4 __attribute__((ext_vector_type(4)));

// fp16 2-limb split: x == hi + lo + O(2^-24 x)  (Sterbenz-exact residual)
__device__ __forceinline__ void split8(const float* v, f16x8& hi, f16x8& lo) {
    #pragma unroll
    for (int u = 0; u < 8; ++u) {
        const _Float16 h = (_Float16)v[u];
        hi[u] = h;
        lo[u] = (_Float16)(v[u] - (float)h);
    }
}
// XOR-swizzled granule index for the 128^2 kernels (proven conflict-free, R5)
#define GIX(g) ((g) ^ ((((g) >> 7) & 3) << 1))

// ---------------------------------------------------------------------------
// fp32 -> fp16 weight pre-convert
// ---------------------------------------------------------------------------
__global__ __launch_bounds__(256) void wconv_kernel(
    const float* __restrict__ src, _Float16* __restrict__ dst, int n4)
{
    const int stride = gridDim.x * blockDim.x;
    for (int i = blockIdx.x * blockDim.x + threadIdx.x; i < n4; i += stride) {
        const float4 v = reinterpret_cast<const float4*>(src)[i];
        f16x2 a = {(_Float16)v.x, (_Float16)v.y};
        f16x2 b = {(_Float16)v.z, (_Float16)v.w};
        reinterpret_cast<f16x2*>(dst)[i * 2 + 0] = a;
        reinterpret_cast<f16x2*>(dst)[i * 2 + 1] = b;
    }
}

// ---------------------------------------------------------------------------
// q GEMM: 256x256 tile, 8 waves (2 x 4), BK=32, fp16x3 split (fp32-class).
// Writes qbuf fp16, rowmean fp32 (exact in-wave), and per-(batch,slot)
// channel sum/max partials (deterministic reduction order throughout).
// Each wave owns 128 rows x 64 cols = exactly one head column-slice.
// ---------------------------------------------------------------------------
__global__ __launch_bounds__(512, 2) void gemm_q_kernel(
    const float* __restrict__ A, const float* __restrict__ W,
    const float* __restrict__ bias, _Float16* __restrict__ Cq,
    float* __restrict__ rowmean, float* __restrict__ psumA,
    float* __restrict__ pmaxA)
{
    const int K = CDIM, N = CDIM;
    __shared__ f16x8 AhiS[1024], AloS[1024], BhiS[1024], BloS[1024]; // 64 KB
    const int tid = threadIdx.x;
    const int lane = tid & 63, wid = tid >> 6;
    const int wr = wid >> 2, wc = wid & 3;
    const int g = lane >> 4, l15 = lane & 15;
    // XCD-chunked swizzle over 1176 blocks (392 x 3), by-fastest in-chunk
    const int bid = blockIdx.x;
    const int v = (bid & 7) * 147 + (bid >> 3);
    const int bx = v / 3, by = v % 3;
    const int mBase = bx * 256, nBase = by * 256;

    f32x4 acc[8][4] = {};

    for (int kt = 0; kt < K; kt += 32) {
        __syncthreads();
        #pragma unroll
        for (int p = 0; p < 2; ++p) {
            const int G = tid + p * 512;
            const int row = G & 255, kc = G >> 8;
            const int gi = kc * 256 + row;
            {
                const float* ap = &A[(size_t)(mBase + row) * K + kt + kc * 8];
                float av[8];
                *reinterpret_cast<float4*>(&av[0]) = *reinterpret_cast<const float4*>(ap);
                *reinterpret_cast<float4*>(&av[4]) = *reinterpret_cast<const float4*>(ap + 4);
                f16x8 h, l; split8(av, h, l);
                AhiS[gi] = h; AloS[gi] = l;
            }
            {
                const float* wp = &W[(size_t)(nBase + row) * K + kt + kc * 8];
                float wv[8];
                *reinterpret_cast<float4*>(&wv[0]) = *reinterpret_cast<const float4*>(wp);
                *reinterpret_cast<float4*>(&wv[4]) = *reinterpret_cast<const float4*>(wp + 4);
                f16x8 h, l; split8(wv, h, l);
                BhiS[gi] = h; BloS[gi] = l;
            }
        }
        __syncthreads();

        f16x8 bh[4], bl[4];
        #pragma unroll
        for (int j = 0; j < 4; ++j) {
            const int gb = g * 256 + wc * 64 + j * 16 + l15;
            bh[j] = BhiS[gb]; bl[j] = BloS[gb];
        }
        #pragma unroll
        for (int i = 0; i < 8; ++i) {
            const int ga = g * 256 + wr * 128 + i * 16 + l15;
            const f16x8 ah = AhiS[ga];
            const f16x8 al = AloS[ga];
            #pragma unroll
            for (int j = 0; j < 4; ++j) {
                acc[i][j] = __builtin_amdgcn_mfma_f32_16x16x32_f16(ah, bh[j], acc[i][j], 0, 0, 0);
                acc[i][j] = __builtin_amdgcn_mfma_f32_16x16x32_f16(ah, bl[j], acc[i][j], 0, 0, 0);
                acc[i][j] = __builtin_amdgcn_mfma_f32_16x16x32_f16(al, bh[j], acc[i][j], 0, 0, 0);
            }
        }
    }

    const int head = by * 4 + wc;

    // ---- C write (fp16, + bias)
    #pragma unroll
    for (int i = 0; i < 8; ++i) {
        #pragma unroll
        for (int j = 0; j < 4; ++j) {
            const int col = nBase + wc * 64 + j * 16 + l15;
            const float bv = bias[col];
            #pragma unroll
            for (int r = 0; r < 4; ++r) {
                const int rowg = mBase + wr * 128 + i * 16 + g * 4 + r;
                Cq[(size_t)rowg * N + col] = (_Float16)(acc[i][j][r] + bv);
            }
        }
    }

    // ---- rowmean (exact, deterministic): sum over this wave's 64 head cols
    float bsum = 0.f;
    #pragma unroll
    for (int j = 0; j < 4; ++j) bsum += bias[nBase + wc * 64 + j * 16 + l15];
    #pragma unroll
    for (int off = 1; off < 16; off <<= 1) bsum += __shfl_xor(bsum, off);

    const int R0 = mBase + wr * 128;
    #pragma unroll
    for (int i = 0; i < 8; ++i) {
        #pragma unroll
        for (int r = 0; r < 4; ++r) {
            float s = acc[i][0][r] + acc[i][1][r] + acc[i][2][r] + acc[i][3][r];
            #pragma unroll
            for (int off = 1; off < 16; off <<= 1) s += __shfl_xor(s, off);
            if (l15 == 0)
                rowmean[(size_t)(R0 + i * 16 + g * 4 + r) * NHEAD + head] =
                    (s + bsum) * (1.0f / 64.0f);
        }
    }

    // ---- channel sum/max partials per batch segment (<=4 batches per wave)
    const int slot = R0 >> 7;
    const int bS = R0 / NTOK, bE = (R0 + 127) / NTOK;
    for (int b = bS; b <= bE; ++b) {
        const int lo = (49 * b > R0 ? 49 * b - R0 : 0);
        const int hiB = 49 * b + 49;
        const int hi = (hiB < R0 + 128 ? hiB - R0 : 128);
        float ps[4] = {0.f, 0.f, 0.f, 0.f};
        float pm[4] = {-INFINITY, -INFINITY, -INFINITY, -INFINITY};
        #pragma unroll
        for (int i = 0; i < 8; ++i) {
            #pragma unroll
            for (int r = 0; r < 4; ++r) {
                const int rl_ = i * 16 + g * 4 + r;
                if (rl_ >= lo && rl_ < hi) {
                    #pragma unroll
                    for (int j = 0; j < 4; ++j) {
                        ps[j] += acc[i][j][r];
                        pm[j] = fmaxf(pm[j], acc[i][j][r]);
                    }
                }
            }
        }
        #pragma unroll
        for (int j = 0; j < 4; ++j) {
            ps[j] += __shfl_xor(ps[j], 16);
            ps[j] += __shfl_xor(ps[j], 32);
            pm[j] = fmaxf(pm[j], __shfl_xor(pm[j], 16));
            pm[j] = fmaxf(pm[j], __shfl_xor(pm[j], 32));
        }
        const int which = slot - ((49 * b) >> 7); // 0 or 1
        if (lane < 16) {
            #pragma unroll
            for (int j = 0; j < 4; ++j) {
                const int idx = ((b * 2 + which) * NHEAD + head) * 64 + j * 16 + lane;
                psumA[idx] = ps[j];
                pmaxA[idx] = pm[j];
            }
        }
    }
}

// ---------------------------------------------------------------------------
// Combine partials + top-k selections (channel + spatial).
// Rank-based selection == lax.top_k tie-break + jnp.sort.
// ---------------------------------------------------------------------------
__global__ __launch_bounds__(64) void topk_kernel(
    const float* __restrict__ psumA, const float* __restrict__ pmaxA,
    const float* __restrict__ rowmean, const float* __restrict__ bq,
    const float* __restrict__ Wc, const float* __restrict__ bc,
    int* __restrict__ cidx, int* __restrict__ p)
{
    const int blk = blockIdx.x;
    const int b = blk / NHEAD, nh = blk % NHEAD;
    const int tid = threadIdx.x; // 64 threads = 1 wave

    __shared__ float chmean[64], chmax[64], rs[NTOK], logits[64];

    {
        const int i0 = ((b * 2 + 0) * NHEAD + nh) * 64 + tid;
        float s = psumA[i0];
        float m = pmaxA[i0];
        if (((49 * b) >> 7) != ((49 * b + 48) >> 7)) {
            const int i1 = ((b * 2 + 1) * NHEAD + nh) * 64 + tid;
            s += psumA[i1];
            m = fmaxf(m, pmaxA[i1]);
        }
        const float bqv = bq[nh * 64 + tid];
        chmean[tid] = s * (1.0f / 49.0f) + bqv;
        chmax[tid] = m + bqv;
    }
    if (tid < NTOK) rs[tid] = rowmean[(size_t)(b * NTOK + tid) * NHEAD + nh];
    __syncthreads();

    float accv = bc[tid];
    const float* wrow = Wc + tid * 128;
    for (int c = 0; c < 64; c++) accv += chmean[c] * wrow[c];
    for (int c = 0; c < 64; c++) accv += chmax[c] * wrow[64 + c];
    const float gl = 0.5f * accv * (1.0f + erff(accv * 0.70710678118654752f));
    logits[tid] = gl;
    __syncthreads();

    int rank = 0;
    for (int kk = 0; kk < 64; kk++) {
        const float o = logits[kk];
        rank += (o > gl) || (o == gl && kk < tid);
    }
    const bool sel = rank < HD2;
    const unsigned long long mask = __ballot(sel);
    if (sel) {
        const int pos = __popcll(mask & ((1ull << tid) - 1ull));
        cidx[blk * HD2 + pos] = tid;
    }
    __syncthreads();

    if (tid < NTOK) {
        const float rv = rs[tid];
        int rank2 = 0;
        for (int m = 0; m < NTOK; m++) {
            const float o = rs[m];
            rank2 += (o > rv) || (o == rv && m < tid);
        }
        const bool sel2 = rank2 < TSEL;
        const unsigned long long mask2 = __ballot(sel2);
        if (sel2) {
            const int pos = __popcll(mask2 & ((1ull << tid) - 1ull));
            p[blk * TSEL + pos] = tid;
        }
    }
}

// ---------------------------------------------------------------------------
// Plain-fp16 GEMM (1 MFMA product), post-decision paths. 128x128 tile.
// MODE 0: A = fp16 row-major (o buffer), fp32 output
// MODE 1: A = channel-gather from fp16 q (cidx), fp16 output (k)
// MODE 2: A = token-gather rows from fp16 q (pidx), fp16 output (v)
// 1D grid with XCD-chunked swizzle; F = col-blocks (by fastest in-chunk).
// ---------------------------------------------------------------------------
template <int MODE>
__global__ __launch_bounds__(256) void gemm_f16_kernel(
    const void* __restrict__ Asrc, const _Float16* __restrict__ Bw,
    const float* __restrict__ bias, void* __restrict__ Cout,
    int N, int K, int PER, int F, const int* __restrict__ gidx)
{
    __shared__ f16x8 AS[512], BS[512];
    const int tid = threadIdx.x;
    const int lane = tid & 63, wid = tid >> 6;
    const int wr = wid >> 1, wc = wid & 1;
    const int bid = blockIdx.x;
    const int vv = (bid & 7) * PER + (bid >> 3);
    const int mBase = (vv / F) * 128, nBase = (vv % F) * 128;
    const int rsub = tid >> 2, kc = tid & 3;

    f32x4 acc[4][4] = {};

    for (int kt = 0; kt < K; kt += 32) {
        __syncthreads();
        #pragma unroll
        for (int pass = 0; pass < 2; ++pass) {
            const int row = rsub + pass * 64;
            const int g = kc * 128 + row;
            const int gi = GIX(g);
            const int kg = kt + kc * 8;
            if (MODE == 0) {
                const _Float16* ap = (const _Float16*)Asrc;
                AS[gi] = *reinterpret_cast<const f16x8*>(
                    &ap[(size_t)(mBase + row) * K + kg]);
            } else if (MODE == 1) {
                const _Float16* Q = (const _Float16*)Asrc;
                const int gm = mBase + row;
                const int b = gm / NTOK;
                const int nh = kg >> 5;
                const int* cp = &gidx[(b * NHEAD + nh) * HD2 + (kg & 31)];
                const int4 c0 = *reinterpret_cast<const int4*>(cp);
                const int4 c1 = *reinterpret_cast<const int4*>(cp + 4);
                const _Float16* qp = &Q[(size_t)gm * CDIM + nh * HDIM];
                f16x8 h;
                h[0] = qp[c0.x]; h[1] = qp[c0.y]; h[2] = qp[c0.z]; h[3] = qp[c0.w];
                h[4] = qp[c1.x]; h[5] = qp[c1.y]; h[6] = qp[c1.z]; h[7] = qp[c1.w];
                AS[gi] = h;
            } else { // MODE 2
                const _Float16* Q = (const _Float16*)Asrc;
                const int gm = mBase + row;
                const int b = gm >> 5, t = gm & 31;
                const int nh = kg >> 6;
                const int row2 = gidx[(b * NHEAD + nh) * TSEL + t];
                AS[gi] = *reinterpret_cast<const f16x8*>(
                    &Q[(size_t)(b * NTOK + row2) * CDIM + kg]);
            }
            BS[gi] = *reinterpret_cast<const f16x8*>(
                &Bw[(size_t)(nBase + row) * K + kg]);
        }
        __syncthreads();

        const int ksl = (lane >> 4) << 7;
        const int rl = lane & 15;
        f16x8 af[4], bf[4];
        #pragma unroll
        for (int f = 0; f < 4; ++f) {
            af[f] = AS[GIX(ksl + wr * 64 + f * 16 + rl)];
            bf[f] = BS[GIX(ksl + wc * 64 + f * 16 + rl)];
        }
        #pragma unroll
        for (int i = 0; i < 4; ++i)
            #pragma unroll
            for (int j = 0; j < 4; ++j)
                acc[i][j] = __builtin_amdgcn_mfma_f32_16x16x32_f16(af[i], bf[j], acc[i][j], 0, 0, 0);
    }

    #pragma unroll
    for (int i = 0; i < 4; ++i) {
        const int rbase = mBase + wr * 64 + i * 16 + ((lane >> 4) << 2);
        #pragma unroll
        for (int j = 0; j < 4; ++j) {
            const int col = nBase + wc * 64 + j * 16 + (lane & 15);
            const float bv = bias[col];
            #pragma unroll
            for (int r = 0; r < 4; ++r) {
                const float o = acc[i][j][r] + bv;
                if (MODE == 0)
                    ((float*)Cout)[(size_t)(rbase + r) * N + col] = o;
                else
                    ((_Float16*)Cout)[(size_t)(rbase + r) * N + col] = (_Float16)o;
            }
        }
    }
}

// ---------------------------------------------------------------------------
// Per (b, nh) attention; 128 threads (2 waves).  q/k/v fp16 in, o fp16 out.
// fp32 math throughout.
// ---------------------------------------------------------------------------
__global__ __launch_bounds__(128) void attn_kernel(
    const _Float16* __restrict__ q, const _Float16* __restrict__ k,
    const _Float16* __restrict__ v, const float* __restrict__ bias_table,
    const int* __restrict__ cidx, const int* __restrict__ p,
    _Float16* __restrict__ obuf)
{
    const int blk = blockIdx.x;
    const int b = blk / NHEAD, nh = blk % NHEAD;
    const int tid = threadIdx.x;

    __shared__ int cI[TSEL], pI[TSEL];
    __shared__ float qal[TSEL][33];
    __shared__ float kh[NTOK][33];
    __shared__ float attnS[NTOK][33];
    __shared__ float gateS[NTOK];
    __shared__ float vs[TSEL][65];

    if (tid < TSEL) {
        cI[tid] = cidx[blk * HD2 + tid];
        pI[tid] = p[blk * TSEL + tid];
    }
    __syncthreads();

    for (int idx = tid; idx < TSEL * HD2; idx += 128) {
        const int t = idx >> 5, j = idx & 31;
        qal[t][j] = (float)q[((size_t)(b * NTOK + pI[t])) * CDIM + nh * HDIM + cI[j]] * SCALE_Q;
    }
    for (int idx = tid; idx < NTOK * HD2; idx += 128) {
        const int i = idx >> 5, j = idx & 31;
        kh[i][j] = (float)k[((size_t)(b * NTOK + i)) * C2DIM + nh * HD2 + j];
    }
    for (int idx = tid; idx < TSEL * 8; idx += 128) {
        const int t = idx >> 3, seg = idx & 7;
        const f16x8 vv = *reinterpret_cast<const f16x8*>(
            &v[((size_t)(b * TSEL + t)) * CDIM + nh * HDIM + seg * 8]);
        #pragma unroll
        for (int u = 0; u < 8; ++u) vs[t][seg * 8 + u] = (float)vv[u];
    }
    __syncthreads();

    {
        const int t = tid & 31;
        const int pt = pI[t];
        const int pti = pt / 7, ptj = pt % 7;
        for (int i = tid >> 5; i < NTOK; i += 4) {
            const int ri = i / 7 - pti + 6;
            const int rj = i % 7 - ptj + 6;
            float a = bias_table[(ri * 13 + rj) * NHEAD + nh];
            #pragma unroll
            for (int j = 0; j < HD2; j++) a += kh[i][j] * qal[t][j];
            attnS[i][t] = a;
        }
    }
    __syncthreads();

    if (tid < NTOK) {
        float m = -INFINITY, tot = 0.f;
        for (int tt = 0; tt < TSEL; tt++) {
            const float xv = attnS[tid][tt];
            tot += xv;
            m = fmaxf(m, xv);
        }
        float s = 0.f;
        for (int tt = 0; tt < TSEL; tt++) s += expf(attnS[tid][tt] - m);
        const float inv = 1.0f / s;
        for (int tt = 0; tt < TSEL; tt++)
            attnS[tid][tt] = expf(attnS[tid][tt] - m) * inv;
        gateS[tid] = 1.0f / (1.0f + expf(-tot * (1.0f / 32.0f)));
    }
    __syncthreads();

    {
        const int d2 = (tid & 31) * 2;
        for (int i = tid >> 5; i < NTOK; i += 4) {
            float a0 = 0.f, a1 = 0.f;
            #pragma unroll
            for (int tt = 0; tt < TSEL; tt++) {
                const float w = attnS[i][tt];
                a0 += w * vs[tt][d2];
                a1 += w * vs[tt][d2 + 1];
            }
            const float gg = gateS[i];
            f16x2 o2 = {(_Float16)(a0 * gg), (_Float16)(a1 * gg)};
            *reinterpret_cast<f16x2*>(
                &obuf[((size_t)(b * NTOK + i)) * CDIM + nh * HDIM + d2]) = o2;
        }
    }
}

// ---------------------------------------------------------------------------
extern "C" void kernel_launch(void* const* d_in, const int* in_sizes, int n_in,
                              void* d_out, int out_size, void* d_ws, size_t ws_size,
                              hipStream_t stream)
{
    const float* x = (const float*)d_in[0];
    const float* Wq = (const float*)d_in[1];
    const float* bq = (const float*)d_in[2];
    const float* Wk = (const float*)d_in[3];
    const float* bk = (const float*)d_in[4];
    const float* Wv = (const float*)d_in[5];
    const float* bv = (const float*)d_in[6];
    const float* Wp = (const float*)d_in[7];
    const float* bp = (const float*)d_in[8];
    const float* Wc = (const float*)d_in[9];
    const float* bc = (const float*)d_in[10];
    const float* bias_table = (const float*)d_in[11];
    float* out = (float*)d_out;

    const size_t NQ = (size_t)MROWS * CDIM;
    char* wsp = (char*)d_ws;
    auto alloc = [&](size_t bytes) -> void* {
        void* pp = (void*)wsp;
        wsp += (bytes + 255) & ~(size_t)255;
        return pp;
    };

    _Float16* qbuf = (_Float16*)alloc(NQ * 2);                     // 154 MB
    _Float16* kbf = (_Float16*)alloc((size_t)MROWS * C2DIM * 2);   // 77 MB
    _Float16* vbf = (_Float16*)alloc((size_t)MVROWS * CDIM * 2);   // 100 MB
    _Float16* obf = (_Float16*)alloc(NQ * 2);                      // 154 MB
    float* rowmean = (float*)alloc((size_t)MROWS * NHEAD * 4);     // 4.8 MB
    float* psumA = (float*)alloc((size_t)BATCH * 2 * NHEAD * 64 * 4); // 12.6 MB
    float* pmaxA = (float*)alloc((size_t)BATCH * 2 * NHEAD * 64 * 4); // 12.6 MB
    _Float16* wk16 = (_Float16*)alloc((size_t)C2DIM * C2DIM * 2);
    _Float16* wv16 = (_Float16*)alloc((size_t)CDIM * CDIM * 2);
    _Float16* wp16 = (_Float16*)alloc((size_t)CDIM * CDIM * 2);
    int* cidx = (int*)alloc((size_t)BATCH * NHEAD * HD2 * 4);
    int* pidx = (int*)alloc((size_t)BATCH * NHEAD * TSEL * 4);
    if ((size_t)(wsp - (char*)d_ws) > ws_size) return;

    // 0) pre-convert post-decision weights to fp16
    wconv_kernel<<<144, 256, 0, stream>>>(Wk, wk16, C2DIM * C2DIM / 4);
    wconv_kernel<<<256, 256, 0, stream>>>(Wv, wv16, CDIM * CDIM / 4);
    wconv_kernel<<<256, 256, 0, stream>>>(Wp, wp16, CDIM * CDIM / 4);

    // 1) q = x @ Wq^T + bq (fp16x3, 256^2 tile) + fused stats, fp16 qbuf
    gemm_q_kernel<<<1176, 512, 0, stream>>>(
        x, Wq, bq, qbuf, rowmean, psumA, pmaxA);

    // 2) combine stats + selections
    topk_kernel<<<BATCH * NHEAD, 64, 0, stream>>>(
        psumA, pmaxA, rowmean, bq, Wc, bc, cidx, pidx);

    // 3) k = gather_ch(q) @ Wk^T + bk  (fp16)   grid 784x3 = 2352
    gemm_f16_kernel<1><<<2352, 256, 0, stream>>>(
        qbuf, wk16, bk, kbf, C2DIM, C2DIM, 294, 3, cidx);

    // 4) v = gather_tok(q) @ Wv^T + bv (fp16)   grid 512x6 = 3072
    gemm_f16_kernel<2><<<3072, 256, 0, stream>>>(
        qbuf, wv16, bv, vbf, CDIM, CDIM, 384, 6, pidx);

    // 5) attention -> o fp16
    attn_kernel<<<BATCH * NHEAD, 128, 0, stream>>>(
        qbuf, kbf, vbf, bias_table, cidx, pidx, obf);

    // 6) out = o @ Wp^T + bp (fp16 -> fp32)     grid 784x6 = 4704
    gemm_f16_kernel<0><<<4704, 256, 0, stream>>>(
        obf, wp16, bp, out, CDIM, CDIM, 588, 6, nullptr);
}